// Round 3
// baseline (659.501 us; speedup 1.0000x reference)
//
#include <hip/hip_runtime.h>
#include <math.h>

// KinematicLayer: B=524288 trajectories, T=64 steps.
// psi is a linear recurrence -> prefix-sum; x,y are prefix sums of dx,dy.
//
// R3 = R2 with the nontemporal builtins applied to clang ext_vector_type
// (HIP float4 is a class -> rejected by __builtin_nontemporal_*).
//
// Mapping: 8 lanes per trajectory, 8 timesteps/lane (2x float4 I/O per
// stream). Halves thread count vs R1 -> per-trajectory fixed costs (base
// trig, exp2 decay, scan levels, init loads) halve chip-wide.
// Base angle via raw v_sin_f32/v_cos_f32 (revolutions; |psi|<~6 rad so
// |rev|<1, hw-valid). Division -> v_rcp_f32 (rel err ~2e-7, harmless).
// Per-step sin/cos via small-angle rotation (theta = w*DT, |theta|<~0.03),
// Taylor sd/cm1 exact at f32; dx_turn = r*ds is cancellation-free.
// Nontemporal loads/stores: streams (774 MiB/iter) can't live in L3 anyway.

using f32x4 = __attribute__((ext_vector_type(4))) float;

__global__ __launch_bounds__(256) void kin_scan_kernel(
    const float* __restrict__ speed,
    const float* __restrict__ yaw,
    const float* __restrict__ init_pos,
    const float* __restrict__ init_heading,
    float* __restrict__ out,
    int B)
{
    const float DT    = 0.1f;
    const float IMG_W = 1920.0f;
    const float IMG_H = 1080.0f;
    const float DIAG  = 2202.9071700822459f;  // sqrt(1920^2+1080^2)
    const float INV_W = 1.0f / 1920.0f;
    const float INV_H = 1.0f / 1080.0f;
    const float LOG2_097 = -0.0439433475875970f;   // log2(0.97)
    const float INV_2PI  = 0.15915494309189535f;   // 1/(2*pi)

    const int tid = blockIdx.x * blockDim.x + threadIdx.x;
    const int row = tid >> 3;          // one trajectory per 8 lanes
    if (row >= B) return;
    const int seg = tid & 7;           // lane within the 8-lane segment
    const int t0  = seg * 8;           // first timestep this lane owns

    // ---- coalesced loads: 8 consecutive timesteps per lane (2 float4s) ----
    const f32x4* sp4 = reinterpret_cast<const f32x4*>(speed) + (size_t)row * 16 + seg * 2;
    const f32x4* yw4 = reinterpret_cast<const f32x4*>(yaw)   + (size_t)row * 16 + seg * 2;
    f32x4 va = __builtin_nontemporal_load(sp4);
    f32x4 vb = __builtin_nontemporal_load(sp4 + 1);
    f32x4 wa = __builtin_nontemporal_load(yw4);
    f32x4 wb = __builtin_nontemporal_load(yw4 + 1);

    // ---- yaw decay 0.97^t : one v_exp_f32 + multiply chain ----
    float d = __builtin_amdgcn_exp2f((float)t0 * LOG2_097);
    float wv[8], vv[8];
    wv[0] = wa.x * d; d *= 0.97f;
    wv[1] = wa.y * d; d *= 0.97f;
    wv[2] = wa.z * d; d *= 0.97f;
    wv[3] = wa.w * d; d *= 0.97f;
    wv[4] = wb.x * d; d *= 0.97f;
    wv[5] = wb.y * d; d *= 0.97f;
    wv[6] = wb.z * d; d *= 0.97f;
    wv[7] = wb.w * d;
    vv[0] = va.x * DIAG; vv[1] = va.y * DIAG; vv[2] = va.z * DIAG; vv[3] = va.w * DIAG;
    vv[4] = vb.x * DIAG; vv[5] = vb.y * DIAG; vv[6] = vb.z * DIAG; vv[7] = vb.w * DIAG;

    // ---- psi scan: local sum then segmented exclusive scan over 8 lanes ----
    float wl = ((((((wv[0] + wv[1]) + wv[2]) + wv[3]) + wv[4]) + wv[5]) + wv[6]) + wv[7];
    float s  = wl;
    #pragma unroll
    for (int dlt = 1; dlt < 8; dlt <<= 1) {
        float o = __shfl_up(s, (unsigned)dlt, 8);
        if (seg >= dlt) s += o;
    }
    float wexcl = s - wl;  // sum of w before t0 (seg==0 -> exactly 0)

    const float psi0 = init_heading[row];
    const float2 ip  = reinterpret_cast<const float2*>(init_pos)[row];
    const float x0   = ip.x * IMG_W;
    const float y0   = ip.y * IMG_H;

    // ---- base angle: raw hw sin/cos in revolutions (|rev| < 1 here) ----
    float p   = psi0 + DT * wexcl;
    float rev = p * INV_2PI;
    float sp  = __builtin_amdgcn_sinf(rev);
    float cp  = __builtin_amdgcn_cosf(rev);

    // ---- 8 steps: carried (sin,cos) rotated by small angle theta = w*DT ----
    float xi[8], yi[8];
    float xacc = 0.0f, yacc = 0.0f;
    #pragma unroll
    for (int j = 0; j < 8; ++j) {
        float v  = vv[j];
        float w  = wv[j];
        float th = w * DT;             // |th| <= ~0.03 for these inputs
        float t2 = th * th;
        float sd  = th * (1.0f + t2 * (-1.666666667e-1f + t2 * 8.333333333e-3f));
        float cm1 = t2 * (-0.5f + t2 * 4.166666667e-2f);
        float ds  = sp * cm1 + cp * sd;   // sin(p+th) - sin(p), cancellation-free
        float dc  = cp * cm1 - sp * sd;   // cos(p+th) - cos(p)
        bool  is_str = fabsf(w) < 0.01f;
        float w_safe = is_str ? (w + 1e-4f) : w;
        float r   = v * __builtin_amdgcn_rcpf(w_safe);  // turn branch: |w|>=0.01
        float dxv = is_str ? (v * cp * DT) : ( r * ds);
        float dyv = is_str ? (v * sp * DT) : (-r * dc);
        xacc += dxv; xi[j] = xacc;        // local inclusive prefix
        yacc += dyv; yi[j] = yacc;
        sp += ds; cp += dc;
    }

    // ---- segmented exclusive scans for x and y (interleaved, 3 levels) ----
    float xs = xi[7], ys = yi[7];
    #pragma unroll
    for (int dlt = 1; dlt < 8; dlt <<= 1) {
        float ox = __shfl_up(xs, (unsigned)dlt, 8);
        float oy = __shfl_up(ys, (unsigned)dlt, 8);
        if (seg >= dlt) { xs += ox; ys += oy; }
    }
    float xb = (xs - xi[7]) + x0;   // x just before this lane's first step
    float yb = (ys - yi[7]) + y0;

    // ---- normalized outputs, 4x float4 nontemporal stores ----
    f32x4* op = reinterpret_cast<f32x4*>(out) + (size_t)row * 32 + seg * 4;
    #pragma unroll
    for (int k = 0; k < 4; ++k) {
        f32x4 o;
        o.x = (xb + xi[2*k    ]) * INV_W;
        o.y = (yb + yi[2*k    ]) * INV_H;
        o.z = (xb + xi[2*k + 1]) * INV_W;
        o.w = (yb + yi[2*k + 1]) * INV_H;
        __builtin_nontemporal_store(o, op + k);
    }
}

extern "C" void kernel_launch(void* const* d_in, const int* in_sizes, int n_in,
                              void* d_out, int out_size, void* d_ws, size_t ws_size,
                              hipStream_t stream) {
    const float* speed        = (const float*)d_in[0];
    const float* yaw_rate     = (const float*)d_in[1];
    const float* init_pos     = (const float*)d_in[2];
    const float* init_heading = (const float*)d_in[3];
    float* out = (float*)d_out;

    const int B = in_sizes[3];                 // init_heading has B elements
    const int threads = 256;
    const int total   = B * 8;                 // 8 lanes per trajectory
    const int blocks  = (total + threads - 1) / threads;

    kin_scan_kernel<<<blocks, threads, 0, stream>>>(
        speed, yaw_rate, init_pos, init_heading, out, B);
}